// Round 3
// baseline (511.721 us; speedup 1.0000x reference)
//
#include <hip/hip_runtime.h>
#include <stdint.h>

#define BB   2
#define SS   2048
#define DD   1024
#define HH   16
#define DKK  64
#define MM   (BB*SS)   // 4096 rows total

typedef __attribute__((ext_vector_type(4))) float f32x4;
typedef __attribute__((ext_vector_type(8))) short s16x8;

#define MFMA_B16(a, b, c) __builtin_amdgcn_mfma_f32_16x16x32_bf16((a), (b), (c), 0, 0, 0)

__device__ __forceinline__ ushort f2bf(float f) {
  uint u = __float_as_uint(f);
  u += 0x7FFFu + ((u >> 16) & 1u);   // round-to-nearest-even
  return (ushort)(u >> 16);
}
__device__ __forceinline__ float bf2f(ushort u) {
  return __uint_as_float((uint)u << 16);
}

// ---------------- fp32 -> bf16 convert (8 elems/thread) ----------------
__global__ void cvt_kernel(const float* __restrict__ src, ushort* __restrict__ dst, int n) {
  int i = (blockIdx.x * 256 + threadIdx.x) * 8;
  if (i >= n) return;
  const float4* s4 = (const float4*)(src + i);
  float4 a = s4[0], b = s4[1];
  union { ushort u[8]; s16x8 v; } r;
  r.u[0] = f2bf(a.x); r.u[1] = f2bf(a.y); r.u[2] = f2bf(a.z); r.u[3] = f2bf(a.w);
  r.u[4] = f2bf(b.x); r.u[5] = f2bf(b.y); r.u[6] = f2bf(b.z); r.u[7] = f2bf(b.w);
  *(s16x8*)(dst + i) = r.v;
}

// ---------------- combine 4 bf16 split-K partials -> bf16 ----------------
__global__ void combine4_kernel(const ushort* __restrict__ p, ushort* __restrict__ dst, int n) {
  int i = (blockIdx.x * 256 + threadIdx.x) * 8;
  if (i >= n) return;
  union { ushort u[8]; s16x8 v; } a, b, c, d, r;
  a.v = *(const s16x8*)(p + i);
  b.v = *(const s16x8*)(p + (size_t)n + i);
  c.v = *(const s16x8*)(p + 2 * (size_t)n + i);
  d.v = *(const s16x8*)(p + 3 * (size_t)n + i);
#pragma unroll
  for (int j = 0; j < 8; ++j)
    r.u[j] = f2bf(bf2f(a.u[j]) + bf2f(b.u[j]) + bf2f(c.u[j]) + bf2f(d.u[j]));
  *(s16x8*)(dst + i) = r.v;
}

// ---------------- Y = A @ W^T  (A:[4096,1024] bf16, W:[1024,1024] bf16) ----------------
// mode 0: Q-proj -> [B,H,S,DK] bf16, scaled by 1/8
// mode 1: K-proj -> [B,H,S,DK] bf16
// mode 2: V-proj -> [B,H,DK,S] bf16 (transposed)
// mode 3: O-proj -> [4096,1024] fp32 (d_out)
__global__ __launch_bounds__(256, 2) void proj_gemm(
    const ushort* __restrict__ A, const ushort* __restrict__ W,
    void* __restrict__ outp, int mode)
{
  __shared__ ushort As[128 * 32];
  __shared__ ushort Bs[128 * 32];
  const int tid  = threadIdx.x;
  const int lane = tid & 63, wave = tid >> 6;
  const int q = lane & 15, g = lane >> 4;
  const int wr = wave >> 1, wc = wave & 1;
  const int mblk = blockIdx.x * 128, nblk = blockIdx.y * 128;

  f32x4 acc[4][4];
  {
    f32x4 z = {0.f, 0.f, 0.f, 0.f};
#pragma unroll
    for (int i = 0; i < 4; ++i)
#pragma unroll
      for (int j = 0; j < 4; ++j) acc[i][j] = z;
  }

  const int r0 = tid >> 2;            // staging row
  const int e0 = (tid & 3) * 8;       // staging element offset within row
  for (int k0 = 0; k0 < 1024; k0 += 32) {
#pragma unroll
    for (int it = 0; it < 2; ++it) {
      const int row = r0 + it * 64;
      *(s16x8*)&As[row * 32 + e0] = *(const s16x8*)(A + (size_t)(mblk + row) * 1024 + k0 + e0);
      *(s16x8*)&Bs[row * 32 + e0] = *(const s16x8*)(W + (size_t)(nblk + row) * 1024 + k0 + e0);
    }
    __syncthreads();
    s16x8 af[4], bf[4];
#pragma unroll
    for (int t = 0; t < 4; ++t) {
      af[t] = *(const s16x8*)&As[(wr * 64 + t * 16 + q) * 32 + g * 8];
      bf[t] = *(const s16x8*)&Bs[(wc * 64 + t * 16 + q) * 32 + g * 8];
    }
#pragma unroll
    for (int mt = 0; mt < 4; ++mt)
#pragma unroll
      for (int nt = 0; nt < 4; ++nt)
        acc[mt][nt] = MFMA_B16(af[mt], bf[nt], acc[mt][nt]);
    __syncthreads();
  }

  // epilogue: C layout col = lane&15 (N), row = (lane>>4)*4 + j (M)
  if (mode == 3) {
    float* O = (float*)outp;
#pragma unroll
    for (int mt = 0; mt < 4; ++mt)
#pragma unroll
      for (int nt = 0; nt < 4; ++nt)
#pragma unroll
        for (int j = 0; j < 4; ++j) {
          const int s = mblk + wr * 64 + mt * 16 + g * 4 + j;
          const int o = nblk + wc * 64 + nt * 16 + q;
          O[(size_t)s * DD + o] = acc[mt][nt][j];
        }
  } else if (mode == 2) {
    ushort* Vt = (ushort*)outp;
#pragma unroll
    for (int mt = 0; mt < 4; ++mt)
#pragma unroll
      for (int nt = 0; nt < 4; ++nt) {
        const int s0 = mblk + wr * 64 + mt * 16 + g * 4;
        const int o  = nblk + wc * 64 + nt * 16 + q;
        const int h = o >> 6, dk = o & 63;
        const int b = s0 >> 11, sr = s0 & 2047;
        ushort4 pk;
        pk.x = f2bf(acc[mt][nt][0]); pk.y = f2bf(acc[mt][nt][1]);
        pk.z = f2bf(acc[mt][nt][2]); pk.w = f2bf(acc[mt][nt][3]);
        *(ushort4*)(Vt + ((size_t)((b * 16 + h) * 64 + dk)) * SS + sr) = pk;
      }
  } else {
    // Q/K proj: LDS-staged epilogue -> full-row contiguous 16B/lane stores.
    // Output head tile is a single head (64 cols) per wave: rows contiguous 128B.
    const float scale = (mode == 0) ? 0.125f : 1.0f;
    ushort* P = (ushort*)outp;
    ushort* wl = As + wave * 1024;   // 2KB wave-private staging (reuse As)
    const int h0 = (nblk + wc * 64) >> 6;
#pragma unroll
    for (int mt = 0; mt < 4; ++mt) {
      const int s0 = mblk + wr * 64 + mt * 16;
      const int b  = s0 >> 11, sr0 = s0 & 2047;
#pragma unroll
      for (int nt = 0; nt < 4; ++nt)
#pragma unroll
        for (int j = 0; j < 4; ++j)
          wl[(g * 4 + j) * 64 + nt * 16 + q] = f2bf(acc[mt][nt][j] * scale);
      // same-wave LDS write->read: compiler inserts lgkmcnt wait
#pragma unroll
      for (int it = 0; it < 2; ++it) {
        s16x8 v = *(const s16x8*)((char*)wl + it * 1024 + lane * 16);
        const int lr = it * 8 + (lane >> 3);
        const int c  = (lane & 7) * 8;
        *(s16x8*)(P + ((size_t)((b * 16 + h0) * SS) + sr0 + lr) * DKK + c) = v;
      }
    }
  }
}

// ---------------- fused attention with head-axis softmax ----------------
// grid 512: bid&7 = b*4+sk (pins each (b,sk) K/V chunk, 2MB, to one XCD's L2),
// bid>>3 = qb (64 q-tiles of 32 rows).  block 512 = 8 waves: qi = wave>>2
// (q-subtile of 16), wh = wave&3 (head group of 4).  512 keys per block,
// 16 macro-iters x 32 keys, each as two 16-key score phases (ONE barrier each,
// psum double-buffered) + one K=32 PV.  attn_sm is wave-private.
// Epilogue staged through LDS for full-line coalesced stores.
__global__ __launch_bounds__(512, 4) void attn_kernel(
    const ushort* __restrict__ Qp, const ushort* __restrict__ Kp,
    const ushort* __restrict__ Vt, ushort* __restrict__ Part)
{
  __shared__ float  psum[4096];      // [buf2][qi2][r4][g4][q16][slot4]  16 KB
  __shared__ ushort attn_sm[16384];  // 8 waves x 4 KB                    32 KB

  const int tid  = threadIdx.x;
  const int lane = tid & 63;
  const int wave = tid >> 6;
  const int qi   = wave >> 2;
  const int wh   = wave & 3;
  const int q    = lane & 15;
  const int g    = lane >> 4;
  const int bid  = blockIdx.x;
  const int bsk  = bid & 7;
  const int b    = bsk >> 2, sk = bsk & 3;
  const int qb   = bid >> 3;
  const int qrow = qb * 32 + qi * 16;
  const int k0   = sk * 512;

  // hoist Q fragments (B-operand: col=lane&15 -> q-row, dk contiguous per g)
  s16x8 qf[4][2];
#pragma unroll
  for (int i = 0; i < 4; ++i) {
    const int h = wh * 4 + i;
    const ushort* Qb = Qp + ((size_t)(b * 16 + h) * SS + qrow + q) * DKK + g * 8;
    qf[i][0] = *(const s16x8*)(Qb);
    qf[i][1] = *(const s16x8*)(Qb + 32);
  }
  const ushort* K0 = Kp + ((size_t)(b * 16 + wh * 4) * SS + k0 + q) * DKK + g * 8;
  const ushort* V0 = Vt + ((size_t)(b * 16 + wh * 4) * DKK + q) * SS + k0 + g * 8;

  f32x4 acc[4][4];
  {
    f32x4 z = {0.f, 0.f, 0.f, 0.f};
#pragma unroll
    for (int i = 0; i < 4; ++i)
#pragma unroll
      for (int n = 0; n < 4; ++n) acc[i][n] = z;
  }

  char* aw = (char*)attn_sm + wave * 4096;   // wave-private 4 KB
  const int swz  = (q & 3) << 4;
  const int slot = wh ^ g;
  float* pq = psum + qi * 1024;
  int buf = 0;

  for (int kt = 0; kt < 16; ++kt) {
#pragma unroll
    for (int ph = 0; ph < 2; ++ph) {
      const int koff = (kt * 32 + ph * 16) * DKK;
      float e[4][4];
      float ps[4] = {0.f, 0.f, 0.f, 0.f};
#pragma unroll
      for (int i = 0; i < 4; ++i) {
        const ushort* Kb = K0 + (size_t)i * SS * DKK + koff;
        f32x4 c = {0.f, 0.f, 0.f, 0.f};
        c = MFMA_B16(*(const s16x8*)(Kb), qf[i][0], c);
        c = MFMA_B16(*(const s16x8*)(Kb + 32), qf[i][1], c);
#pragma unroll
        for (int r = 0; r < 4; ++r) { e[i][r] = __expf(c[r]); ps[r] += e[i][r]; }
      }
      float* pw = pq + buf * 2048;
#pragma unroll
      for (int r = 0; r < 4; ++r)
        pw[((r * 4 + g) * 16 + q) * 4 + slot] = ps[r];
      __syncthreads();
      float rinv[4];
#pragma unroll
      for (int r = 0; r < 4; ++r) {
        f32x4 t = *(const f32x4*)&pw[((r * 4 + g) * 16 + q) * 4];
        rinv[r] = 1.0f / (t[0] + t[1] + t[2] + t[3]);
      }
      // normalized attn (bf16) -> wave-private LDS, swizzled within 64B q-row
#pragma unroll
      for (int i = 0; i < 4; ++i) {
        uint2 pp;
        pp.x = (uint)f2bf(e[i][0] * rinv[0]) | ((uint)f2bf(e[i][1] * rinv[1]) << 16);
        pp.y = (uint)f2bf(e[i][2] * rinv[2]) | ((uint)f2bf(e[i][3] * rinv[3]) << 16);
        *(uint2*)(aw + (i * 16 + q) * 64 + ((ph * 32 + g * 8) ^ swz)) = pp;
      }
      buf ^= 1;
    }
    // PV over the full 32-key tile: A = attn row q (8 k per lane), B = V^T rows
#pragma unroll
    for (int i = 0; i < 4; ++i) {
      s16x8 pa = *(const s16x8*)(aw + (i * 16 + q) * 64 + ((g * 16) ^ swz));
      const ushort* Vb = V0 + (size_t)i * DKK * SS + kt * 32;
#pragma unroll
      for (int n = 0; n < 4; ++n)
        acc[i][n] = MFMA_B16(pa, *(const s16x8*)(Vb + n * 16 * SS), acc[i][n]);
    }
  }

  // epilogue: stage per-wave 16 rows x 128 cols (2 heads) in LDS, then
  // coalesced 16B/lane stores (each instr: 4 rows x 256B contiguous).
  ushort* P = Part + (size_t)sk * MM * DD + ((size_t)(b * SS) + qrow) * DD;
  ushort* aw16 = (ushort*)aw;
#pragma unroll
  for (int hp = 0; hp < 2; ++hp) {
#pragma unroll
    for (int ih = 0; ih < 2; ++ih) {
      const int i = hp * 2 + ih;
#pragma unroll
      for (int n = 0; n < 4; ++n)
#pragma unroll
        for (int j = 0; j < 4; ++j)
          aw16[(g * 4 + j) * 128 + ih * 64 + n * 16 + q] = f2bf(acc[i][n][j]);
    }
    // same-wave LDS write->read (lgkmcnt handled by compiler)
#pragma unroll
    for (int it = 0; it < 4; ++it) {
      s16x8 v = *(const s16x8*)(aw + it * 1024 + lane * 16);
      const int lr = it * 4 + (lane >> 4);
      const int c  = (lane & 15) * 8;
      *(s16x8*)(P + (size_t)lr * DD + (wh * 4 + hp * 2) * 64 + c) = v;
    }
  }
}

extern "C" void kernel_launch(void* const* d_in, const int* in_sizes, int n_in,
                              void* d_out, int out_size, void* d_ws, size_t ws_size,
                              hipStream_t stream) {
  const float* Query = (const float*)d_in[0];
  const float* Key   = (const float*)d_in[1];
  const float* Value = (const float*)d_in[2];
  const float* Wq    = (const float*)d_in[3];
  const float* Wk    = (const float*)d_in[4];
  const float* Wv    = (const float*)d_in[5];
  const float* Wo    = (const float*)d_in[6];

  size_t off = 0;
  char* ws = (char*)d_ws;
  auto alloc = [&](size_t bytes) -> void* {
    void* p = ws + off;
    off += (bytes + 255) & ~(size_t)255;
    return p;
  };
  const size_t nX = (size_t)MM * DD;   // 4194304
  const size_t nW = (size_t)DD * DD;   // 1048576
  ushort* Xq  = (ushort*)alloc(nX * 2);
  ushort* Xk  = (ushort*)alloc(nX * 2);
  ushort* Xv  = (ushort*)alloc(nX * 2);
  ushort* Wqb = (ushort*)alloc(nW * 2);
  ushort* Wkb = (ushort*)alloc(nW * 2);
  ushort* Wvb = (ushort*)alloc(nW * 2);
  ushort* Wob = (ushort*)alloc(nW * 2);
  ushort* Qp  = (ushort*)alloc(nX * 2);
  ushort* Kp  = (ushort*)alloc(nX * 2);
  ushort* Vtb = (ushort*)alloc(nX * 2);
  ushort* Part = (ushort*)alloc(4 * nX * 2);   // 4 bf16 split-K partials
  ushort* Ctx = (ushort*)alloc(nX * 2);

  cvt_kernel<<<(int)(nX / 2048), 256, 0, stream>>>(Query, Xq, (int)nX);
  cvt_kernel<<<(int)(nX / 2048), 256, 0, stream>>>(Key,   Xk, (int)nX);
  cvt_kernel<<<(int)(nX / 2048), 256, 0, stream>>>(Value, Xv, (int)nX);
  cvt_kernel<<<(int)(nW / 2048), 256, 0, stream>>>(Wq, Wqb, (int)nW);
  cvt_kernel<<<(int)(nW / 2048), 256, 0, stream>>>(Wk, Wkb, (int)nW);
  cvt_kernel<<<(int)(nW / 2048), 256, 0, stream>>>(Wv, Wvb, (int)nW);
  cvt_kernel<<<(int)(nW / 2048), 256, 0, stream>>>(Wo, Wob, (int)nW);

  dim3 pg(32, 8), pb(256);
  proj_gemm<<<pg, pb, 0, stream>>>(Xq, Wqb, Qp, 0);
  proj_gemm<<<pg, pb, 0, stream>>>(Xk, Wkb, Kp, 1);
  proj_gemm<<<pg, pb, 0, stream>>>(Xv, Wvb, Vtb, 2);

  attn_kernel<<<512, 512, 0, stream>>>(Qp, Kp, Vtb, Part);

  combine4_kernel<<<(int)(nX / 2048), 256, 0, stream>>>(Part, Ctx, (int)nX);

  proj_gemm<<<pg, pb, 0, stream>>>(Ctx, Wob, d_out, 3);
}

// Round 4
// 424.945 us; speedup vs baseline: 1.2042x; 1.2042x over previous
//
#include <hip/hip_runtime.h>
#include <stdint.h>

#define BB   2
#define SS   2048
#define DD   1024
#define HH   16
#define DKK  64
#define MM   (BB*SS)   // 4096 rows total

typedef __attribute__((ext_vector_type(4))) float f32x4;
typedef __attribute__((ext_vector_type(8))) short s16x8;

#define MFMA_B16(a, b, c) __builtin_amdgcn_mfma_f32_16x16x32_bf16((a), (b), (c), 0, 0, 0)

__device__ __forceinline__ ushort f2bf(float f) {
  uint u = __float_as_uint(f);
  u += 0x7FFFu + ((u >> 16) & 1u);   // round-to-nearest-even
  return (ushort)(u >> 16);
}
__device__ __forceinline__ float bf2f(ushort u) {
  return __uint_as_float((uint)u << 16);
}

// ---------------- fp32 -> bf16 convert (8 elems/thread) ----------------
__global__ void cvt_kernel(const float* __restrict__ src, ushort* __restrict__ dst, int n) {
  int i = (blockIdx.x * 256 + threadIdx.x) * 8;
  if (i >= n) return;
  const float4* s4 = (const float4*)(src + i);
  float4 a = s4[0], b = s4[1];
  union { ushort u[8]; s16x8 v; } r;
  r.u[0] = f2bf(a.x); r.u[1] = f2bf(a.y); r.u[2] = f2bf(a.z); r.u[3] = f2bf(a.w);
  r.u[4] = f2bf(b.x); r.u[5] = f2bf(b.y); r.u[6] = f2bf(b.z); r.u[7] = f2bf(b.w);
  *(s16x8*)(dst + i) = r.v;
}

// ---------------- combine 4 bf16 split-K partials -> bf16 ----------------
__global__ void combine4_kernel(const ushort* __restrict__ p, ushort* __restrict__ dst, int n) {
  int i = (blockIdx.x * 256 + threadIdx.x) * 8;
  if (i >= n) return;
  union { ushort u[8]; s16x8 v; } a, b, c, d, r;
  a.v = *(const s16x8*)(p + i);
  b.v = *(const s16x8*)(p + (size_t)n + i);
  c.v = *(const s16x8*)(p + 2 * (size_t)n + i);
  d.v = *(const s16x8*)(p + 3 * (size_t)n + i);
#pragma unroll
  for (int j = 0; j < 8; ++j)
    r.u[j] = f2bf(bf2f(a.u[j]) + bf2f(b.u[j]) + bf2f(c.u[j]) + bf2f(d.u[j]));
  *(s16x8*)(dst + i) = r.v;
}

// ---------------- Y = A @ W^T  (A:[4096,1024] bf16, W:[1024,1024] bf16) ----------------
// mode 0: Q-proj -> [B,H,S,DK] bf16, scaled by 1/8
// mode 1: K-proj -> [B,H,S,DK] bf16
// mode 2: V-proj -> [B,H,DK,S] bf16 (transposed)
// mode 3: O-proj -> [4096,1024] fp32 (d_out)
__global__ __launch_bounds__(256, 2) void proj_gemm(
    const ushort* __restrict__ A, const ushort* __restrict__ W,
    void* __restrict__ outp, int mode)
{
  __shared__ ushort As[128 * 32];
  __shared__ ushort Bs[128 * 32];
  const int tid  = threadIdx.x;
  const int lane = tid & 63, wave = tid >> 6;
  const int q = lane & 15, g = lane >> 4;
  const int wr = wave >> 1, wc = wave & 1;
  const int mblk = blockIdx.x * 128, nblk = blockIdx.y * 128;

  f32x4 acc[4][4];
  {
    f32x4 z = {0.f, 0.f, 0.f, 0.f};
#pragma unroll
    for (int i = 0; i < 4; ++i)
#pragma unroll
      for (int j = 0; j < 4; ++j) acc[i][j] = z;
  }

  const int r0 = tid >> 2;            // staging row
  const int e0 = (tid & 3) * 8;       // staging element offset within row
  for (int k0 = 0; k0 < 1024; k0 += 32) {
#pragma unroll
    for (int it = 0; it < 2; ++it) {
      const int row = r0 + it * 64;
      *(s16x8*)&As[row * 32 + e0] = *(const s16x8*)(A + (size_t)(mblk + row) * 1024 + k0 + e0);
      *(s16x8*)&Bs[row * 32 + e0] = *(const s16x8*)(W + (size_t)(nblk + row) * 1024 + k0 + e0);
    }
    __syncthreads();
    s16x8 af[4], bf[4];
#pragma unroll
    for (int t = 0; t < 4; ++t) {
      af[t] = *(const s16x8*)&As[(wr * 64 + t * 16 + q) * 32 + g * 8];
      bf[t] = *(const s16x8*)&Bs[(wc * 64 + t * 16 + q) * 32 + g * 8];
    }
#pragma unroll
    for (int mt = 0; mt < 4; ++mt)
#pragma unroll
      for (int nt = 0; nt < 4; ++nt)
        acc[mt][nt] = MFMA_B16(af[mt], bf[nt], acc[mt][nt]);
    __syncthreads();
  }

  // epilogue: C layout col = lane&15 (N), row = (lane>>4)*4 + j (M)
  if (mode == 3) {
    float* O = (float*)outp;
#pragma unroll
    for (int mt = 0; mt < 4; ++mt)
#pragma unroll
      for (int nt = 0; nt < 4; ++nt)
#pragma unroll
        for (int j = 0; j < 4; ++j) {
          const int s = mblk + wr * 64 + mt * 16 + g * 4 + j;
          const int o = nblk + wc * 64 + nt * 16 + q;
          O[(size_t)s * DD + o] = acc[mt][nt][j];
        }
  } else if (mode == 2) {
    ushort* Vt = (ushort*)outp;
#pragma unroll
    for (int mt = 0; mt < 4; ++mt)
#pragma unroll
      for (int nt = 0; nt < 4; ++nt) {
        const int s0 = mblk + wr * 64 + mt * 16 + g * 4;
        const int o  = nblk + wc * 64 + nt * 16 + q;
        const int h = o >> 6, dk = o & 63;
        const int b = s0 >> 11, sr = s0 & 2047;
        ushort4 pk;
        pk.x = f2bf(acc[mt][nt][0]); pk.y = f2bf(acc[mt][nt][1]);
        pk.z = f2bf(acc[mt][nt][2]); pk.w = f2bf(acc[mt][nt][3]);
        *(ushort4*)(Vt + ((size_t)((b * 16 + h) * 64 + dk)) * SS + sr) = pk;
      }
  } else {
    // Q/K proj: LDS-staged epilogue -> full-row contiguous 16B/lane stores.
    // Output head tile is a single head (64 cols) per wave: rows contiguous 128B.
    const float scale = (mode == 0) ? 0.125f : 1.0f;
    ushort* P = (ushort*)outp;
    ushort* wl = As + wave * 1024;   // 2KB wave-private staging (reuse As)
    const int h0 = (nblk + wc * 64) >> 6;
#pragma unroll
    for (int mt = 0; mt < 4; ++mt) {
      const int s0 = mblk + wr * 64 + mt * 16;
      const int b  = s0 >> 11, sr0 = s0 & 2047;
#pragma unroll
      for (int nt = 0; nt < 4; ++nt)
#pragma unroll
        for (int j = 0; j < 4; ++j)
          wl[(g * 4 + j) * 64 + nt * 16 + q] = f2bf(acc[mt][nt][j] * scale);
      // same-wave LDS write->read: compiler inserts lgkmcnt wait
#pragma unroll
      for (int it = 0; it < 2; ++it) {
        s16x8 v = *(const s16x8*)((char*)wl + it * 1024 + lane * 16);
        const int lr = it * 8 + (lane >> 3);
        const int c  = (lane & 7) * 8;
        *(s16x8*)(P + ((size_t)((b * 16 + h0) * SS) + sr0 + lr) * DKK + c) = v;
      }
    }
  }
}

// ---------------- fused attention with head-axis softmax ----------------
// grid 512: bid&7 = b*4+sk (pins each (b,sk) K/V chunk, 2MB, to one XCD's L2),
// bid>>3 = qb (64 q-tiles of 32 rows).  block 512 = 8 waves: qi = wave>>2
// (q-subtile of 16), wh = wave&3 (head group of 4).  512 keys per block,
// 16 macro-iters x 32 keys, each as two 16-key score phases (ONE barrier each,
// psum double-buffered) + one K=32 PV.  attn_sm is wave-private.
// __launch_bounds__(512,2): min_waves=4 capped VGPRs at 64 and spilled the
// accumulators to scratch (~0.9 GB traffic, R2/R3 post-mortem) — min_waves=2
// gives the allocator room (~112-160 VGPR); at <=128 VGPR 2 blocks/CU fit.
__global__ __launch_bounds__(512, 2) void attn_kernel(
    const ushort* __restrict__ Qp, const ushort* __restrict__ Kp,
    const ushort* __restrict__ Vt, ushort* __restrict__ Part)
{
  __shared__ float  psum[4096];      // [buf2][qi2][r4][g4][q16][slot4]  16 KB
  __shared__ ushort attn_sm[16384];  // 8 waves x 4 KB                    32 KB

  const int tid  = threadIdx.x;
  const int lane = tid & 63;
  const int wave = tid >> 6;
  const int qi   = wave >> 2;
  const int wh   = wave & 3;
  const int q    = lane & 15;
  const int g    = lane >> 4;
  const int bid  = blockIdx.x;
  const int bsk  = bid & 7;
  const int b    = bsk >> 2, sk = bsk & 3;
  const int qb   = bid >> 3;
  const int qrow = qb * 32 + qi * 16;
  const int k0   = sk * 512;

  // hoist Q fragments (B-operand: col=lane&15 -> q-row, dk contiguous per g)
  s16x8 qf[4][2];
#pragma unroll
  for (int i = 0; i < 4; ++i) {
    const int h = wh * 4 + i;
    const ushort* Qb = Qp + ((size_t)(b * 16 + h) * SS + qrow + q) * DKK + g * 8;
    qf[i][0] = *(const s16x8*)(Qb);
    qf[i][1] = *(const s16x8*)(Qb + 32);
  }
  const ushort* K0 = Kp + ((size_t)(b * 16 + wh * 4) * SS + k0 + q) * DKK + g * 8;
  const ushort* V0 = Vt + ((size_t)(b * 16 + wh * 4) * DKK + q) * SS + k0 + g * 8;

  f32x4 acc[4][4];
  {
    f32x4 z = {0.f, 0.f, 0.f, 0.f};
#pragma unroll
    for (int i = 0; i < 4; ++i)
#pragma unroll
      for (int n = 0; n < 4; ++n) acc[i][n] = z;
  }

  char* aw = (char*)attn_sm + wave * 4096;   // wave-private 4 KB
  const int swz  = (q & 3) << 4;
  const int slot = wh ^ g;
  float* pq = psum + qi * 1024;
  int buf = 0;

  for (int kt = 0; kt < 16; ++kt) {
#pragma unroll
    for (int ph = 0; ph < 2; ++ph) {
      const int koff = (kt * 32 + ph * 16) * DKK;
      float e[4][4];
      float ps[4] = {0.f, 0.f, 0.f, 0.f};
#pragma unroll
      for (int i = 0; i < 4; ++i) {
        const ushort* Kb = K0 + (size_t)i * SS * DKK + koff;
        f32x4 c = {0.f, 0.f, 0.f, 0.f};
        c = MFMA_B16(*(const s16x8*)(Kb), qf[i][0], c);
        c = MFMA_B16(*(const s16x8*)(Kb + 32), qf[i][1], c);
#pragma unroll
        for (int r = 0; r < 4; ++r) { e[i][r] = __expf(c[r]); ps[r] += e[i][r]; }
      }
      float* pw = pq + buf * 2048;
#pragma unroll
      for (int r = 0; r < 4; ++r)
        pw[((r * 4 + g) * 16 + q) * 4 + slot] = ps[r];
      __syncthreads();
      float rinv[4];
#pragma unroll
      for (int r = 0; r < 4; ++r) {
        f32x4 t = *(const f32x4*)&pw[((r * 4 + g) * 16 + q) * 4];
        rinv[r] = 1.0f / (t[0] + t[1] + t[2] + t[3]);
      }
      // normalized attn (bf16) -> wave-private LDS, swizzled within 64B q-row
#pragma unroll
      for (int i = 0; i < 4; ++i) {
        uint2 pp;
        pp.x = (uint)f2bf(e[i][0] * rinv[0]) | ((uint)f2bf(e[i][1] * rinv[1]) << 16);
        pp.y = (uint)f2bf(e[i][2] * rinv[2]) | ((uint)f2bf(e[i][3] * rinv[3]) << 16);
        *(uint2*)(aw + (i * 16 + q) * 64 + ((ph * 32 + g * 8) ^ swz)) = pp;
      }
      buf ^= 1;
    }
    // PV over the full 32-key tile: A = attn row q (8 k per lane), B = V^T rows
#pragma unroll
    for (int i = 0; i < 4; ++i) {
      s16x8 pa = *(const s16x8*)(aw + (i * 16 + q) * 64 + ((g * 16) ^ swz));
      const ushort* Vb = V0 + (size_t)i * DKK * SS + kt * 32;
#pragma unroll
      for (int n = 0; n < 4; ++n)
        acc[i][n] = MFMA_B16(pa, *(const s16x8*)(Vb + n * 16 * SS), acc[i][n]);
    }
  }

  // epilogue: stage per-wave 16 rows x 128 cols (2 heads) in LDS, then
  // coalesced 16B/lane stores (each instr: 4 rows x 256B contiguous).
  ushort* P = Part + (size_t)sk * MM * DD + ((size_t)(b * SS) + qrow) * DD;
  ushort* aw16 = (ushort*)aw;
#pragma unroll
  for (int hp = 0; hp < 2; ++hp) {
#pragma unroll
    for (int ih = 0; ih < 2; ++ih) {
      const int i = hp * 2 + ih;
#pragma unroll
      for (int n = 0; n < 4; ++n)
#pragma unroll
        for (int j = 0; j < 4; ++j)
          aw16[(g * 4 + j) * 128 + ih * 64 + n * 16 + q] = f2bf(acc[i][n][j]);
    }
    // same-wave LDS write->read (lgkmcnt handled by compiler)
#pragma unroll
    for (int it = 0; it < 4; ++it) {
      s16x8 v = *(const s16x8*)(aw + it * 1024 + lane * 16);
      const int lr = it * 4 + (lane >> 4);
      const int c  = (lane & 15) * 8;
      *(s16x8*)(P + (size_t)lr * DD + (wh * 4 + hp * 2) * 64 + c) = v;
    }
  }
}

extern "C" void kernel_launch(void* const* d_in, const int* in_sizes, int n_in,
                              void* d_out, int out_size, void* d_ws, size_t ws_size,
                              hipStream_t stream) {
  const float* Query = (const float*)d_in[0];
  const float* Key   = (const float*)d_in[1];
  const float* Value = (const float*)d_in[2];
  const float* Wq    = (const float*)d_in[3];
  const float* Wk    = (const float*)d_in[4];
  const float* Wv    = (const float*)d_in[5];
  const float* Wo    = (const float*)d_in[6];

  size_t off = 0;
  char* ws = (char*)d_ws;
  auto alloc = [&](size_t bytes) -> void* {
    void* p = ws + off;
    off += (bytes + 255) & ~(size_t)255;
    return p;
  };
  const size_t nX = (size_t)MM * DD;   // 4194304
  const size_t nW = (size_t)DD * DD;   // 1048576
  ushort* Xq  = (ushort*)alloc(nX * 2);
  ushort* Xk  = (ushort*)alloc(nX * 2);
  ushort* Xv  = (ushort*)alloc(nX * 2);
  ushort* Wqb = (ushort*)alloc(nW * 2);
  ushort* Wkb = (ushort*)alloc(nW * 2);
  ushort* Wvb = (ushort*)alloc(nW * 2);
  ushort* Wob = (ushort*)alloc(nW * 2);
  ushort* Qp  = (ushort*)alloc(nX * 2);
  ushort* Kp  = (ushort*)alloc(nX * 2);
  ushort* Vtb = (ushort*)alloc(nX * 2);
  ushort* Part = (ushort*)alloc(4 * nX * 2);   // 4 bf16 split-K partials
  ushort* Ctx = (ushort*)alloc(nX * 2);

  cvt_kernel<<<(int)(nX / 2048), 256, 0, stream>>>(Query, Xq, (int)nX);
  cvt_kernel<<<(int)(nX / 2048), 256, 0, stream>>>(Key,   Xk, (int)nX);
  cvt_kernel<<<(int)(nX / 2048), 256, 0, stream>>>(Value, Xv, (int)nX);
  cvt_kernel<<<(int)(nW / 2048), 256, 0, stream>>>(Wq, Wqb, (int)nW);
  cvt_kernel<<<(int)(nW / 2048), 256, 0, stream>>>(Wk, Wkb, (int)nW);
  cvt_kernel<<<(int)(nW / 2048), 256, 0, stream>>>(Wv, Wvb, (int)nW);
  cvt_kernel<<<(int)(nW / 2048), 256, 0, stream>>>(Wo, Wob, (int)nW);

  dim3 pg(32, 8), pb(256);
  proj_gemm<<<pg, pb, 0, stream>>>(Xq, Wqb, Qp, 0);
  proj_gemm<<<pg, pb, 0, stream>>>(Xk, Wkb, Kp, 1);
  proj_gemm<<<pg, pb, 0, stream>>>(Xv, Wvb, Vtb, 2);

  attn_kernel<<<512, 512, 0, stream>>>(Qp, Kp, Vtb, Part);

  combine4_kernel<<<(int)(nX / 2048), 256, 0, stream>>>(Part, Ctx, (int)nX);

  proj_gemm<<<pg, pb, 0, stream>>>(Ctx, Wob, d_out, 3);
}

// Round 5
// 363.305 us; speedup vs baseline: 1.4085x; 1.1697x over previous
//
#include <hip/hip_runtime.h>
#include <stdint.h>

#define BB   2
#define SS   2048
#define DD   1024
#define HH   16
#define DKK  64
#define MM   (BB*SS)   // 4096 rows total

typedef __attribute__((ext_vector_type(4))) float f32x4;
typedef __attribute__((ext_vector_type(8))) short s16x8;

#define MFMA_B16(a, b, c) __builtin_amdgcn_mfma_f32_16x16x32_bf16((a), (b), (c), 0, 0, 0)

__device__ __forceinline__ ushort f2bf(float f) {
  uint u = __float_as_uint(f);
  u += 0x7FFFu + ((u >> 16) & 1u);   // round-to-nearest-even
  return (ushort)(u >> 16);
}
__device__ __forceinline__ float bf2f(ushort u) {
  return __uint_as_float((uint)u << 16);
}

// ---------------- fp32 -> bf16 convert (8 elems/thread) ----------------
__global__ void cvt_kernel(const float* __restrict__ src, ushort* __restrict__ dst, int n) {
  int i = (blockIdx.x * 256 + threadIdx.x) * 8;
  if (i >= n) return;
  const float4* s4 = (const float4*)(src + i);
  float4 a = s4[0], b = s4[1];
  union { ushort u[8]; s16x8 v; } r;
  r.u[0] = f2bf(a.x); r.u[1] = f2bf(a.y); r.u[2] = f2bf(a.z); r.u[3] = f2bf(a.w);
  r.u[4] = f2bf(b.x); r.u[5] = f2bf(b.y); r.u[6] = f2bf(b.z); r.u[7] = f2bf(b.w);
  *(s16x8*)(dst + i) = r.v;
}

// ---------------- combine 4 bf16 split-K partials -> bf16 ----------------
__global__ void combine4_kernel(const ushort* __restrict__ p, ushort* __restrict__ dst, int n) {
  int i = (blockIdx.x * 256 + threadIdx.x) * 8;
  if (i >= n) return;
  union { ushort u[8]; s16x8 v; } a, b, c, d, r;
  a.v = *(const s16x8*)(p + i);
  b.v = *(const s16x8*)(p + (size_t)n + i);
  c.v = *(const s16x8*)(p + 2 * (size_t)n + i);
  d.v = *(const s16x8*)(p + 3 * (size_t)n + i);
#pragma unroll
  for (int j = 0; j < 8; ++j)
    r.u[j] = f2bf(bf2f(a.u[j]) + bf2f(b.u[j]) + bf2f(c.u[j]) + bf2f(d.u[j]));
  *(s16x8*)(dst + i) = r.v;
}

// ---------------- Y = A @ W^T  (A:[4096,1024] bf16, W:[1024,1024] bf16) ----------------
// mode 0: Q-proj -> [B,H,S,DK] bf16, scaled by 1/8
// mode 1: K-proj -> [B,H,S,DK] bf16
// mode 2: V-proj -> [B,H,DK,S] bf16 (transposed)
// mode 3: O-proj -> [4096,1024] fp32 (d_out)
__global__ __launch_bounds__(256, 2) void proj_gemm(
    const ushort* __restrict__ A, const ushort* __restrict__ W,
    void* __restrict__ outp, int mode)
{
  __shared__ ushort As[128 * 32];
  __shared__ ushort Bs[128 * 32];
  const int tid  = threadIdx.x;
  const int lane = tid & 63, wave = tid >> 6;
  const int q = lane & 15, g = lane >> 4;
  const int wr = wave >> 1, wc = wave & 1;
  const int mblk = blockIdx.x * 128, nblk = blockIdx.y * 128;

  f32x4 acc[4][4];
  {
    f32x4 z = {0.f, 0.f, 0.f, 0.f};
#pragma unroll
    for (int i = 0; i < 4; ++i)
#pragma unroll
      for (int j = 0; j < 4; ++j) acc[i][j] = z;
  }

  const int r0 = tid >> 2;            // staging row
  const int e0 = (tid & 3) * 8;       // staging element offset within row
  for (int k0 = 0; k0 < 1024; k0 += 32) {
#pragma unroll
    for (int it = 0; it < 2; ++it) {
      const int row = r0 + it * 64;
      *(s16x8*)&As[row * 32 + e0] = *(const s16x8*)(A + (size_t)(mblk + row) * 1024 + k0 + e0);
      *(s16x8*)&Bs[row * 32 + e0] = *(const s16x8*)(W + (size_t)(nblk + row) * 1024 + k0 + e0);
    }
    __syncthreads();
    s16x8 af[4], bf[4];
#pragma unroll
    for (int t = 0; t < 4; ++t) {
      af[t] = *(const s16x8*)&As[(wr * 64 + t * 16 + q) * 32 + g * 8];
      bf[t] = *(const s16x8*)&Bs[(wc * 64 + t * 16 + q) * 32 + g * 8];
    }
#pragma unroll
    for (int mt = 0; mt < 4; ++mt)
#pragma unroll
      for (int nt = 0; nt < 4; ++nt)
        acc[mt][nt] = MFMA_B16(af[mt], bf[nt], acc[mt][nt]);
    __syncthreads();
  }

  // epilogue: C layout col = lane&15 (N), row = (lane>>4)*4 + j (M)
  if (mode == 3) {
    float* O = (float*)outp;
#pragma unroll
    for (int mt = 0; mt < 4; ++mt)
#pragma unroll
      for (int nt = 0; nt < 4; ++nt)
#pragma unroll
        for (int j = 0; j < 4; ++j) {
          const int s = mblk + wr * 64 + mt * 16 + g * 4 + j;
          const int o = nblk + wc * 64 + nt * 16 + q;
          O[(size_t)s * DD + o] = acc[mt][nt][j];
        }
  } else if (mode == 2) {
    ushort* Vt = (ushort*)outp;
#pragma unroll
    for (int mt = 0; mt < 4; ++mt)
#pragma unroll
      for (int nt = 0; nt < 4; ++nt) {
        const int s0 = mblk + wr * 64 + mt * 16 + g * 4;
        const int o  = nblk + wc * 64 + nt * 16 + q;
        const int h = o >> 6, dk = o & 63;
        const int b = s0 >> 11, sr = s0 & 2047;
        ushort4 pk;
        pk.x = f2bf(acc[mt][nt][0]); pk.y = f2bf(acc[mt][nt][1]);
        pk.z = f2bf(acc[mt][nt][2]); pk.w = f2bf(acc[mt][nt][3]);
        *(ushort4*)(Vt + ((size_t)((b * 16 + h) * 64 + dk)) * SS + sr) = pk;
      }
  } else {
    // Q/K proj: LDS-staged epilogue -> full-row contiguous 16B/lane stores.
    const float scale = (mode == 0) ? 0.125f : 1.0f;
    ushort* P = (ushort*)outp;
    ushort* wl = As + wave * 1024;   // 2KB wave-private staging (reuse As)
    const int h0 = (nblk + wc * 64) >> 6;
#pragma unroll
    for (int mt = 0; mt < 4; ++mt) {
      const int s0 = mblk + wr * 64 + mt * 16;
      const int b  = s0 >> 11, sr0 = s0 & 2047;
#pragma unroll
      for (int nt = 0; nt < 4; ++nt)
#pragma unroll
        for (int j = 0; j < 4; ++j)
          wl[(g * 4 + j) * 64 + nt * 16 + q] = f2bf(acc[mt][nt][j] * scale);
      // same-wave LDS write->read: compiler inserts lgkmcnt wait
#pragma unroll
      for (int it = 0; it < 2; ++it) {
        s16x8 v = *(const s16x8*)((char*)wl + it * 1024 + lane * 16);
        const int lr = it * 8 + (lane >> 3);
        const int c  = (lane & 7) * 8;
        *(s16x8*)(P + ((size_t)((b * 16 + h0) * SS) + sr0 + lr) * DKK + c) = v;
      }
    }
  }
}

// ---------------- fused attention with head-axis softmax ----------------
// grid 1024: bid&7 = b*4+sk (XCD pin, 2MB K/V chunk L2-resident), bid>>3 = qb
// (128 q-tiles of 16 rows).  block 256 = 4 waves, wave wh owns heads wh*4..+3.
// 512 keys/block, 16 phases x 32 keys.  Per phase: rolling K-prefetch (subtile
// B issued before A's MFMAs, next-A issued before B's MFMAs), in-register expf,
// ONE barrier for the 4-slot psum exchange (double-buffered), wave-private attn
// LDS re-layout, K=32 PV with direct V operand loads.
// launch_bounds (256,2): cap 256 VGPR (min_waves>=3 caused 64-VGPR spill, R2/R3).
__global__ __launch_bounds__(256, 2) void attn_kernel(
    const ushort* __restrict__ Qp, const ushort* __restrict__ Kp,
    const ushort* __restrict__ Vt, ushort* __restrict__ Part)
{
  __shared__ float  psum[2][2048];   // [buf][ks2][r4][g4][q16][slot4]  16 KB
  __shared__ ushort attn_sm[8192];   // 4 waves x 4 KB                   16 KB

  const int tid  = threadIdx.x;
  const int lane = tid & 63;
  const int wh   = tid >> 6;         // wave = head group
  const int q    = lane & 15;
  const int g    = lane >> 4;
  const int bid  = blockIdx.x;
  const int bsk  = bid & 7;
  const int b    = bsk >> 2, sk = bsk & 3;
  const int qb   = bid >> 3;
  const int qrow = qb * 16;
  const int k0   = sk * 512;

  // hoist Q fragments (B-operand: col=lane&15 -> q-row, dk contiguous per g)
  s16x8 qf[4][2];
#pragma unroll
  for (int i = 0; i < 4; ++i) {
    const int h = wh * 4 + i;
    const ushort* Qb = Qp + ((size_t)(b * 16 + h) * SS + qrow + q) * DKK + g * 8;
    qf[i][0] = *(const s16x8*)(Qb);
    qf[i][1] = *(const s16x8*)(Qb + 32);
  }
  const ushort* K0 = Kp + ((size_t)(b * 16 + wh * 4) * SS + k0 + q) * DKK + g * 8;
  const ushort* V0 = Vt + ((size_t)(b * 16 + wh * 4) * DKK + q) * SS + k0 + g * 8;

  f32x4 acc[4][4];
  {
    f32x4 z = {0.f, 0.f, 0.f, 0.f};
#pragma unroll
    for (int i = 0; i < 4; ++i)
#pragma unroll
      for (int n = 0; n < 4; ++n) acc[i][n] = z;
  }

  char* aw = (char*)attn_sm + wh * 4096;   // wave-private 4 KB
  const int swz  = (q & 3) << 4;
  const int slot = wh ^ g;
  int buf = 0;

  // prefetch K subtile 0 (keys 0..15 of this chunk)
  s16x8 kA[4][2], kB[4][2];
#pragma unroll
  for (int i = 0; i < 4; ++i) {
    const ushort* Kb = K0 + (size_t)i * SS * DKK;
    kA[i][0] = *(const s16x8*)(Kb);
    kA[i][1] = *(const s16x8*)(Kb + 32);
  }

  for (int kt = 0; kt < 16; ++kt) {
    const int base = kt * 32;
    // issue subtile-B loads (keys base+16..base+31); latency hides under scores-A
#pragma unroll
    for (int i = 0; i < 4; ++i) {
      const ushort* Kb = K0 + (size_t)i * SS * DKK + (base + 16) * DKK;
      kB[i][0] = *(const s16x8*)(Kb);
      kB[i][1] = *(const s16x8*)(Kb + 32);
    }
    // scores A from prefetched kA
    float eA[4][4], eB[4][4];
    float psA[4] = {0.f, 0.f, 0.f, 0.f};
    float psB[4] = {0.f, 0.f, 0.f, 0.f};
#pragma unroll
    for (int i = 0; i < 4; ++i) {
      f32x4 c = {0.f, 0.f, 0.f, 0.f};
      c = MFMA_B16(kA[i][0], qf[i][0], c);
      c = MFMA_B16(kA[i][1], qf[i][1], c);
#pragma unroll
      for (int r = 0; r < 4; ++r) { eA[i][r] = __expf(c[r]); psA[r] += eA[i][r]; }
    }
    // issue next phase's subtile-A loads (keys base+32..); consumed next iter
    if (kt < 15) {
#pragma unroll
      for (int i = 0; i < 4; ++i) {
        const ushort* Kb = K0 + (size_t)i * SS * DKK + (base + 32) * DKK;
        kA[i][0] = *(const s16x8*)(Kb);
        kA[i][1] = *(const s16x8*)(Kb + 32);
      }
    }
    // scores B from kB
#pragma unroll
    for (int i = 0; i < 4; ++i) {
      f32x4 c = {0.f, 0.f, 0.f, 0.f};
      c = MFMA_B16(kB[i][0], qf[i][0], c);
      c = MFMA_B16(kB[i][1], qf[i][1], c);
#pragma unroll
      for (int r = 0; r < 4; ++r) { eB[i][r] = __expf(c[r]); psB[r] += eB[i][r]; }
    }
    // per-wave partial denominators, both 16-key halves, double-buffered
#pragma unroll
    for (int r = 0; r < 4; ++r) {
      psum[buf][((r * 4 + g) * 16 + q) * 4 + slot]             = psA[r];
      psum[buf][(((4 + r) * 4 + g) * 16 + q) * 4 + slot]       = psB[r];
    }
    __syncthreads();
    float rinvA[4], rinvB[4];
#pragma unroll
    for (int r = 0; r < 4; ++r) {
      f32x4 tA = *(const f32x4*)&psum[buf][((r * 4 + g) * 16 + q) * 4];
      f32x4 tB = *(const f32x4*)&psum[buf][(((4 + r) * 4 + g) * 16 + q) * 4];
      rinvA[r] = 1.0f / (tA[0] + tA[1] + tA[2] + tA[3]);
      rinvB[r] = 1.0f / (tB[0] + tB[1] + tB[2] + tB[3]);
    }
    // normalized attn (bf16) -> wave-private LDS, swizzled within 64B q-row
#pragma unroll
    for (int i = 0; i < 4; ++i) {
      uint2 pa, pb;
      pa.x = (uint)f2bf(eA[i][0] * rinvA[0]) | ((uint)f2bf(eA[i][1] * rinvA[1]) << 16);
      pa.y = (uint)f2bf(eA[i][2] * rinvA[2]) | ((uint)f2bf(eA[i][3] * rinvA[3]) << 16);
      pb.x = (uint)f2bf(eB[i][0] * rinvB[0]) | ((uint)f2bf(eB[i][1] * rinvB[1]) << 16);
      pb.y = (uint)f2bf(eB[i][2] * rinvB[2]) | ((uint)f2bf(eB[i][3] * rinvB[3]) << 16);
      const int rowoff = (i * 16 + q) * 64;
      *(uint2*)(aw + rowoff + ((g * 8) ^ swz))      = pa;
      *(uint2*)(aw + rowoff + ((32 + g * 8) ^ swz)) = pb;
    }
    // PV over the 32-key tile: A = attn row q (8 k per lane), B = V^T rows
#pragma unroll
    for (int i = 0; i < 4; ++i) {
      s16x8 pa = *(const s16x8*)(aw + (i * 16 + q) * 64 + ((g * 16) ^ swz));
      const ushort* Vb = V0 + (size_t)i * DKK * SS + base;
#pragma unroll
      for (int n = 0; n < 4; ++n)
        acc[i][n] = MFMA_B16(pa, *(const s16x8*)(Vb + n * 16 * SS), acc[i][n]);
    }
    buf ^= 1;
  }

  // epilogue: stage per-wave 16 rows x 128 cols (2 heads) in LDS, then
  // coalesced 16B/lane stores (each instr: 4 rows x 256B contiguous).
  ushort* P = Part + (size_t)sk * MM * DD + ((size_t)(b * SS) + qrow) * DD;
  ushort* aw16 = (ushort*)aw;
#pragma unroll
  for (int hp = 0; hp < 2; ++hp) {
#pragma unroll
    for (int ih = 0; ih < 2; ++ih) {
      const int i = hp * 2 + ih;
#pragma unroll
      for (int n = 0; n < 4; ++n)
#pragma unroll
        for (int j = 0; j < 4; ++j)
          aw16[(g * 4 + j) * 128 + ih * 64 + n * 16 + q] = f2bf(acc[i][n][j]);
    }
    // same-wave LDS write->read (lgkmcnt handled by compiler)
#pragma unroll
    for (int it = 0; it < 4; ++it) {
      s16x8 v = *(const s16x8*)(aw + it * 1024 + lane * 16);
      const int lr = it * 4 + (lane >> 4);
      const int c  = (lane & 15) * 8;
      *(s16x8*)(P + (size_t)lr * DD + (wh * 4 + hp * 2) * 64 + c) = v;
    }
  }
}

extern "C" void kernel_launch(void* const* d_in, const int* in_sizes, int n_in,
                              void* d_out, int out_size, void* d_ws, size_t ws_size,
                              hipStream_t stream) {
  const float* Query = (const float*)d_in[0];
  const float* Key   = (const float*)d_in[1];
  const float* Value = (const float*)d_in[2];
  const float* Wq    = (const float*)d_in[3];
  const float* Wk    = (const float*)d_in[4];
  const float* Wv    = (const float*)d_in[5];
  const float* Wo    = (const float*)d_in[6];

  size_t off = 0;
  char* ws = (char*)d_ws;
  auto alloc = [&](size_t bytes) -> void* {
    void* p = ws + off;
    off += (bytes + 255) & ~(size_t)255;
    return p;
  };
  const size_t nX = (size_t)MM * DD;   // 4194304
  const size_t nW = (size_t)DD * DD;   // 1048576
  ushort* Xq  = (ushort*)alloc(nX * 2);
  ushort* Xk  = (ushort*)alloc(nX * 2);
  ushort* Xv  = (ushort*)alloc(nX * 2);
  ushort* Wqb = (ushort*)alloc(nW * 2);
  ushort* Wkb = (ushort*)alloc(nW * 2);
  ushort* Wvb = (ushort*)alloc(nW * 2);
  ushort* Wob = (ushort*)alloc(nW * 2);
  ushort* Qp  = (ushort*)alloc(nX * 2);
  ushort* Kp  = (ushort*)alloc(nX * 2);
  ushort* Vtb = (ushort*)alloc(nX * 2);
  ushort* Part = (ushort*)alloc(4 * nX * 2);   // 4 bf16 split-K partials
  ushort* Ctx = (ushort*)alloc(nX * 2);

  cvt_kernel<<<(int)(nX / 2048), 256, 0, stream>>>(Query, Xq, (int)nX);
  cvt_kernel<<<(int)(nX / 2048), 256, 0, stream>>>(Key,   Xk, (int)nX);
  cvt_kernel<<<(int)(nX / 2048), 256, 0, stream>>>(Value, Xv, (int)nX);
  cvt_kernel<<<(int)(nW / 2048), 256, 0, stream>>>(Wq, Wqb, (int)nW);
  cvt_kernel<<<(int)(nW / 2048), 256, 0, stream>>>(Wk, Wkb, (int)nW);
  cvt_kernel<<<(int)(nW / 2048), 256, 0, stream>>>(Wv, Wvb, (int)nW);
  cvt_kernel<<<(int)(nW / 2048), 256, 0, stream>>>(Wo, Wob, (int)nW);

  dim3 pg(32, 8), pb(256);
  proj_gemm<<<pg, pb, 0, stream>>>(Xq, Wqb, Qp, 0);
  proj_gemm<<<pg, pb, 0, stream>>>(Xk, Wkb, Kp, 1);
  proj_gemm<<<pg, pb, 0, stream>>>(Xv, Wvb, Vtb, 2);

  attn_kernel<<<1024, 256, 0, stream>>>(Qp, Kp, Vtb, Part);

  combine4_kernel<<<(int)(nX / 2048), 256, 0, stream>>>(Part, Ctx, (int)nX);

  proj_gemm<<<pg, pb, 0, stream>>>(Ctx, Wob, d_out, 3);
}